// Round 10
// baseline (299.721 us; speedup 1.0000x reference)
//
#include <hip/hip_runtime.h>
#include <stdint.h>

// Problem: B=4, S=2048, D=1024, H=16, HD=64. I/O fp32; internal compute bf16
// MFMA with fp32 accumulation.
// SCALE*log2(e) folded into wq^T and bq -> flash uses exp2 directly with a
// FIXED softmax max of 0 (shift-invariant; logits statically bounded ~|9|).
// Flash v7: 64 q/wave (R9) + PV via mfma_16x16x32 (H2: mfma16 costs the same
// matrix-pipe occupancy as mfma32 at half FLOP -- R9 ran at exactly the
// 206G-equiv/2075TF floor). P^T round-trips through a wave-private packed
// LDS buffer: b64 writes (cvt_pk pairs), b128 B-frag reads, both at the
// uniform bank floor. V back to plain V^T + XOR swizzle, b128 A-frag reads
// (R6 pattern, measured 0 conflicts).

typedef __attribute__((ext_vector_type(8))) short bf16x8;
typedef __attribute__((ext_vector_type(4))) float f32x4;
typedef __attribute__((ext_vector_type(2))) unsigned int u32x2;
typedef unsigned short u16;
typedef unsigned int u32;

#define AS1 __attribute__((address_space(1)))
#define AS3 __attribute__((address_space(3)))

#define SCALE_L2E 0.18033688011112042f  // 0.125 * log2(e)

__device__ __forceinline__ void gld_lds16(const void* g, void* l) {
  // async global->LDS DMA: lane i's 16B land at (wave-uniform) l + i*16
  __builtin_amdgcn_global_load_lds((const AS1 void*)g, (AS3 void*)l, 16, 0, 0);
}

__device__ __forceinline__ u16 f2bf(float f) {
  u32 x = __builtin_bit_cast(u32, f);
  x += 0x7fff + ((x >> 16) & 1);  // RNE
  return (u16)(x >> 16);
}

__device__ __forceinline__ u16 f2bf_fast(float a) {
#if __has_builtin(__builtin_amdgcn_cvt_pk_bf16_f32)
  auto v = __builtin_amdgcn_cvt_pk_bf16_f32(a, a);  // both halves = a: order-immune
  return (u16)(__builtin_bit_cast(u32, v) & 0xffffu);
#else
  return f2bf(a);
#endif
}

__device__ __forceinline__ u32 pk2(float a, float b) {  // lo16=a, hi16=b
#if __has_builtin(__builtin_amdgcn_cvt_pk_bf16_f32)
  return __builtin_bit_cast(u32, __builtin_amdgcn_cvt_pk_bf16_f32(a, b));
#else
  return (u32)f2bf(a) | ((u32)f2bf(b) << 16);
#endif
}

__device__ __forceinline__ float exp2_fast(float x) {
#if __has_builtin(__builtin_amdgcn_exp2f)
  return __builtin_amdgcn_exp2f(x);
#else
  return exp2f(x);
#endif
}

// ---------------------------------------------------------------------------
// fp32 -> bf16 conversion of x (8M elements)
// ---------------------------------------------------------------------------
__global__ __launch_bounds__(256) void convert_x(const float* __restrict__ x,
                                                 u16* __restrict__ xb) {
  int i = (blockIdx.x * 256 + threadIdx.x) * 4;
  float4 v = *(const float4*)(x + i);
  ushort4 o;
  o.x = f2bf(v.x); o.y = f2bf(v.y); o.z = f2bf(v.z); o.w = f2bf(v.w);
  *(ushort4*)(xb + i) = o;
}

// ---------------------------------------------------------------------------
// Weight pack (fp32 [K][N] -> bf16 [N][K]); wq scaled by SCALE*log2(e)
// ---------------------------------------------------------------------------
__global__ __launch_bounds__(256) void pack_weights(
    const float* __restrict__ wq, const float* __restrict__ wk,
    const float* __restrict__ wv, const float* __restrict__ wo,
    u16* __restrict__ wt_qkv, u16* __restrict__ wt_o) {
  __shared__ float tile[64][65];
  int mat = blockIdx.z;
  const float* src = (mat == 0) ? wq : (mat == 1) ? wk : (mat == 2) ? wv : wo;
  int k0 = blockIdx.y * 64, j0 = blockIdx.x * 64;
  int t = threadIdx.x;
  int lr = t >> 6;   // 0..3
  int lc = t & 63;
#pragma unroll
  for (int it = 0; it < 16; ++it) {
    int r = it * 4 + lr;
    tile[r][lc] = src[(size_t)(k0 + r) * 1024 + j0 + lc];
  }
  __syncthreads();
  u16* dst = (mat == 3) ? wt_o : (wt_qkv + (size_t)mat * 1024 * 1024);
#pragma unroll
  for (int it = 0; it < 16; ++it) {
    int nl = it * 4 + lr;
    float v = tile[lc][nl];
    if (mat == 0) v *= SCALE_L2E;  // fold attention scale + log2(e)
    dst[(size_t)(j0 + nl) * 1024 + k0 + lc] = f2bf(v);
  }
}

// ---------------------------------------------------------------------------
// GEMM: C[M,N] = A[M,1024](bf16) x Bt[N,1024]^T(bf16) + bias(fp32).
// 128x128 tile, 4 waves 2x2, each wave 4x4 of 16x16x32 bf16 MFMA (m97 struct).
// 1D grid, XCD-swizzled for L2 locality.
// MODE 0: N=3072 fused QKV; scatter: Q,K->[B,H,S,HD] bf16, V->[B,H,HD,S] bf16
//         (V^T stores packed: 4 consecutive s per lane -> one ushort4)
// MODE 1: N=1024; plain row-major fp32 out + bias
// ---------------------------------------------------------------------------
template <int MODE>
__global__ __launch_bounds__(256, 2) void gemm_bt(
    const u16* __restrict__ A, const u16* __restrict__ Bt,
    const float* __restrict__ bias0, const float* __restrict__ bias1,
    const float* __restrict__ bias2,
    void* __restrict__ out0v, void* __restrict__ out1v, void* __restrict__ out2v) {
  __shared__ u16 lA[128 * 32];  // [m][k] rows of 32 bf16 (64B)
  __shared__ u16 lB[128 * 32];  // [n][k]
  const int K = 1024;
  int tid = threadIdx.x;
  int wave = tid >> 6, lane = tid & 63;

  int bid = blockIdx.x;
  int m0, n0;
  if constexpr (MODE == 0) {
    int xcd = bid & 7, j = bid >> 3;      // 192 blocks per XCD
    n0 = (xcd * 3 + j % 3) * 128;         // XCD owns n-tiles 3x..3x+2 (768KB B)
    m0 = (j / 3) * 128;                   // consecutive j share m-tile
  } else {
    n0 = (bid & 7) * 128;                 // XCD owns 1 n-tile (256KB B)
    m0 = (bid >> 3) * 128;
  }
  int wm = (wave & 1) * 64, wn = (wave >> 1) * 64;

  f32x4 acc[4][4];
#pragma unroll
  for (int i = 0; i < 4; ++i)
#pragma unroll
    for (int j = 0; j < 4; ++j) acc[i][j] = f32x4{0.f, 0.f, 0.f, 0.f};

  int srow = lane >> 2;          // source row within 16-row stage
  int scol = (lane & 3) * 8;     // source col chunk within 32

  for (int k0 = 0; k0 < K; k0 += 32) {
#pragma unroll
    for (int c = 0; c < 2; ++c) {
      int rbase = wave * 32 + c * 16;
      gld_lds16(A + (size_t)(m0 + rbase + srow) * K + k0 + scol, lA + rbase * 32);
      gld_lds16(Bt + (size_t)(n0 + rbase + srow) * K + k0 + scol, lB + rbase * 32);
    }
    __syncthreads();
    bf16x8 af[4], bfr[4];
#pragma unroll
    for (int mt = 0; mt < 4; ++mt)
      af[mt] = *(const bf16x8*)(lA + (wm + mt * 16 + (lane & 15)) * 32 + (lane >> 4) * 8);
#pragma unroll
    for (int nt = 0; nt < 4; ++nt)
      bfr[nt] = *(const bf16x8*)(lB + (wn + nt * 16 + (lane & 15)) * 32 + (lane >> 4) * 8);
#pragma unroll
    for (int mt = 0; mt < 4; ++mt)
#pragma unroll
      for (int nt = 0; nt < 4; ++nt)
        acc[mt][nt] = __builtin_amdgcn_mfma_f32_16x16x32_bf16(af[mt], bfr[nt], acc[mt][nt], 0, 0, 0);
    __syncthreads();
  }

  // epilogue: C/D layout row=(lane>>4)*4+r, col=lane&15 (m89-verified)
  int rbase0 = m0 + wm + (lane >> 4) * 4;
  int cbase = n0 + wn + (lane & 15);
#pragma unroll
  for (int nt = 0; nt < 4; ++nt) {
    int col = cbase + nt * 16;
    if constexpr (MODE == 0) {
      int mat = col >> 10, j = col & 1023;
      const float* bp = (mat == 0) ? bias0 : (mat == 1) ? bias1 : bias2;
      float bv = bp[j];
      if (mat == 0) bv *= SCALE_L2E;
      int h = j >> 6, hd = j & 63;
      if (mat == 2) {
        // V^T [B,H,HD,S]: per lane the 4 r-values are consecutive s -> pack
        u16* base = (u16*)out2v;
#pragma unroll
        for (int mt = 0; mt < 4; ++mt) {
          int row0 = rbase0 + mt * 16;  // multiple of 4, no b/s crossing
          int b = row0 >> 11, s = row0 & 2047;
          size_t idx = ((size_t)(b * 16 + h) * 64 + hd) * 2048 + s;
          ushort4 pk;
          pk.x = f2bf_fast(acc[mt][nt][0] + bv);
          pk.y = f2bf_fast(acc[mt][nt][1] + bv);
          pk.z = f2bf_fast(acc[mt][nt][2] + bv);
          pk.w = f2bf_fast(acc[mt][nt][3] + bv);
          *(ushort4*)(base + idx) = pk;
        }
      } else {
        u16* base = (mat == 0) ? (u16*)out0v : (u16*)out1v;
#pragma unroll
        for (int mt = 0; mt < 4; ++mt)
#pragma unroll
          for (int r = 0; r < 4; ++r) {
            int row = rbase0 + mt * 16 + r;
            int b = row >> 11, s = row & 2047;
            size_t idx = ((size_t)(b * 16 + h) * 2048 + s) * 64 + hd;  // [B,H,S,HD]
            base[idx] = f2bf_fast(acc[mt][nt][r] + bv);
          }
      }
    } else {
      float bv = bias0[col];
      float* o = (float*)out0v;
#pragma unroll
      for (int mt = 0; mt < 4; ++mt)
#pragma unroll
        for (int r = 0; r < 4; ++r) {
          int row = rbase0 + mt * 16 + r;
          o[(size_t)row * 1024 + col] = acc[mt][nt][r] + bv;
        }
    }
  }
}

// ---------------------------------------------------------------------------
// Flash attention v7: 64 q/wave, all-x32 MFMA, fixed-max softmax (m=0).
// 1 block per (b, h, 256 q-rows); 4 waves x 64 q (4 q-tiles of 16).
// Per KV-64 iter, per kk (32-s half):
//   for stl=0,1 (st=2kk+stl): S^T = mfma32(A=K-frag, B=Q-frag) per q-tile t;
//     p = exp2(S^T); pack r-pairs -> one ds_write_b64 into wave-private lP
//     (row (t*16+c), stride 20 u32; write bank-pairs uniform)
//   PV: P^T B-frag = one aligned ds_read_b128 per (t,kk) (bank-quads uniform);
//     V^T A-frag = b128 from XOR-swizzled lV (R6 pattern, 0 conflicts);
//     O^T += mfma32(vf, pfrag) per (dt,t).
// Wave-private lP: ds ops in-order per wave -> no barrier for the round-trip.
// ---------------------------------------------------------------------------
__global__ __launch_bounds__(256, 2) void flash_attn(
    const u16* __restrict__ Q, const u16* __restrict__ Kb,
    const u16* __restrict__ Vt, u16* __restrict__ ctx) {
  __shared__ u16 lK[2][64 * 32];   // [k-half][kv-row][32] xor-swizzled (8KB)
  __shared__ u16 lV[2][64 * 32];   // [s-half][d][32] xor-swizzled (8KB)
  __shared__ u32 lP[4][64 * 20];   // [wave][(t*16+c)*20 + word] (20KB)
  int tid = threadIdx.x, wave = tid >> 6, lane = tid & 63;

  int F = blockIdx.x;             // 512 flat blocks
  int xcd = F & 7, idx = F >> 3;  // 64 per XCD
  int bh = xcd * 8 + (idx >> 3);  // 8 bh per XCD
  int q0 = (idx & 7) * 256;
  int b = bh >> 4, h = bh & 15;
  const u16* Qp = Q + (size_t)bh * 2048 * 64;
  const u16* Kp = Kb + (size_t)bh * 2048 * 64;
  const u16* Vp = Vt + (size_t)bh * 64 * 2048;

  int c = lane & 15, g = lane >> 4;

  // Q B-fragments (persistent): lane holds q=c of tile t, k=kk*32+g*8+j
  bf16x8 qf[4][2];
#pragma unroll
  for (int t = 0; t < 4; ++t) {
    const u16* qrow = Qp + (size_t)(q0 + wave * 64 + t * 16 + c) * 64 + g * 8;
    qf[t][0] = *(const bf16x8*)qrow;
    qf[t][1] = *(const bf16x8*)(qrow + 32);
  }

  float lsum[4] = {0.f, 0.f, 0.f, 0.f};  // per-lane: q=c of tile t
  f32x4 o[4][4];                          // O^T[d=dt*16+4g+r][q=c] per tile t
#pragma unroll
  for (int t = 0; t < 4; ++t)
#pragma unroll
    for (int dt = 0; dt < 4; ++dt) o[t][dt] = f32x4{0.f, 0.f, 0.f, 0.f};

  // staging: lane stages row wave*16+(lane>>2), chunk-pos lane&3;
  // source chunk = pos ^ ((row>>1)&3)   (XOR swizzle; b128 reads conflict-free)
  int srow = lane >> 2;
  int schunk = (((lane & 3) ^ ((lane >> 3) & 3)) * 8);
  int rsw = (c >> 1) & 3;  // read-side swizzle
  int stg_row = wave * 16 + srow;
  u32* pb = lP[wave];

  for (int s0 = 0; s0 < 2048; s0 += 64) {
#pragma unroll
    for (int kk = 0; kk < 2; ++kk) {
      gld_lds16(Kp + (size_t)(s0 + stg_row) * 64 + kk * 32 + schunk,
                lK[kk] + wave * 512);
      gld_lds16(Vp + (size_t)stg_row * 2048 + s0 + kk * 32 + schunk,
                lV[kk] + wave * 512);
    }
    __syncthreads();

#pragma unroll
    for (int kk = 0; kk < 2; ++kk) {
      // ---- S^T + exp2 -> packed P^T rows in wave-private LDS ----
#pragma unroll
      for (int stl = 0; stl < 2; ++stl) {
        int st = kk * 2 + stl;
        // K A-fragments: lane holds kv=st*16+c, k=kh*32+g*8+j
        bf16x8 kf0 = *(const bf16x8*)(lK[0] + (st * 16 + c) * 32 + (g ^ rsw) * 8);
        bf16x8 kf1 = *(const bf16x8*)(lK[1] + (st * 16 + c) * 32 + (g ^ rsw) * 8);
#pragma unroll
        for (int t = 0; t < 4; ++t) {
          f32x4 sa = __builtin_amdgcn_mfma_f32_16x16x32_bf16(kf0, qf[t][0],
                         f32x4{0.f, 0.f, 0.f, 0.f}, 0, 0, 0);
          sa = __builtin_amdgcn_mfma_f32_16x16x32_bf16(kf1, qf[t][1], sa, 0, 0, 0);
          // sa[r] = S^T[s=st*16+4g+r][q=c] (log2 units)
          float p0 = exp2_fast(sa[0]), p1 = exp2_fast(sa[1]);
          float p2 = exp2_fast(sa[2]), p3 = exp2_fast(sa[3]);
          lsum[t] += (p0 + p1) + (p2 + p3);
          u32x2 w; w.x = pk2(p0, p1); w.y = pk2(p2, p3);
          *(u32x2*)(pb + (t * 16 + c) * 20 + stl * 8 + 2 * g) = w;
        }
      }

      // ---- O^T += V^T[:,kk] P^T[kk,:] via mfma32 ----
      bf16x8 vf[4];
#pragma unroll
      for (int dt = 0; dt < 4; ++dt)
        vf[dt] = *(const bf16x8*)(lV[kk] + (dt * 16 + c) * 32 + (g ^ rsw) * 8);
#pragma unroll
      for (int t = 0; t < 4; ++t) {
        bf16x8 pfr = *(const bf16x8*)(pb + (t * 16 + c) * 20 + 4 * g);
#pragma unroll
        for (int dt = 0; dt < 4; ++dt)
          o[t][dt] = __builtin_amdgcn_mfma_f32_16x16x32_bf16(vf[dt], pfr, o[t][dt], 0, 0, 0);
      }
    }
    __syncthreads();
  }

  // epilogue: reduce lsum across the 4 lane-groups sharing q=c, normalize,
  // write ctx[b][q][h][d] as packed ushort4 (d = dt*16+4g+r)
#pragma unroll
  for (int t = 0; t < 4; ++t) {
    float rs = lsum[t];
    rs += __shfl_xor(rs, 16);
    rs += __shfl_xor(rs, 32);
    float inv = 1.0f / fmaxf(rs, 1e-30f);
    int q = q0 + wave * 64 + t * 16 + c;
    size_t rowbase = ((size_t)(b * 2048 + q) * 16 + h) * 64;
#pragma unroll
    for (int dt = 0; dt < 4; ++dt) {
      ushort4 pk;
      pk.x = f2bf_fast(o[t][dt][0] * inv);
      pk.y = f2bf_fast(o[t][dt][1] * inv);
      pk.z = f2bf_fast(o[t][dt][2] * inv);
      pk.w = f2bf_fast(o[t][dt][3] * inv);
      *(ushort4*)(ctx + rowbase + dt * 16 + g * 4) = pk;
    }
  }
}

// ---------------------------------------------------------------------------
extern "C" void kernel_launch(void* const* d_in, const int* in_sizes, int n_in,
                              void* d_out, int out_size, void* d_ws, size_t ws_size,
                              hipStream_t stream) {
  const float* x  = (const float*)d_in[0];
  const float* wq = (const float*)d_in[1];
  const float* bq = (const float*)d_in[2];
  const float* wk = (const float*)d_in[3];
  const float* bk = (const float*)d_in[4];
  const float* wv = (const float*)d_in[5];
  const float* bv = (const float*)d_in[6];
  const float* wo = (const float*)d_in[7];
  const float* bo = (const float*)d_in[8];

  u16* ws = (u16*)d_ws;
  u16* xb     = ws;                            // 8192*1024 bf16 (16MB)
  u16* wt_qkv = xb + (size_t)8192 * 1024;      // 3072*1024 (6MB)
  u16* wt_o   = wt_qkv + (size_t)3072 * 1024;  // 1024*1024 (2MB)
  u16* Qb     = wt_o + (size_t)1024 * 1024;    // [B,H,S,HD] (16MB)
  u16* Kbuf   = Qb + (size_t)8192 * 1024;      // [B,H,S,HD] (16MB)
  u16* Vtb    = Kbuf + (size_t)8192 * 1024;    // [B,H,HD,S] (16MB)
  u16* ctx    = Vtb + (size_t)8192 * 1024;     // [B,S,D] bf16 (16MB)
  // total ws use: 88MB

  convert_x<<<8192, 256, 0, stream>>>(x, xb);
  pack_weights<<<dim3(16, 16, 4), 256, 0, stream>>>(wq, wk, wv, wo, wt_qkv, wt_o);
  gemm_bt<0><<<1536, 256, 0, stream>>>(xb, wt_qkv, bq, bk, bv, Qb, Kbuf, Vtb);
  flash_attn<<<512, 256, 0, stream>>>(Qb, Kbuf, Vtb, ctx);
  gemm_bt<1><<<512, 256, 0, stream>>>(ctx, wt_o, bo, nullptr, nullptr,
                                      d_out, nullptr, nullptr);
}

// Round 11
// 287.209 us; speedup vs baseline: 1.0436x; 1.0436x over previous
//
#include <hip/hip_runtime.h>
#include <stdint.h>

// Problem: B=4, S=2048, D=1024, H=16, HD=64. I/O fp32; internal compute bf16
// MFMA with fp32 accumulation.
// SCALE*log2(e) folded into wq^T and bq -> flash uses exp2 directly with a
// FIXED softmax max of 0 (shift-invariant; logits statically bounded ~|9|).
// Flash = R9 (best: 99.7us): register-resident P via transposed-S mfma16 PV,
// 64 q/wave, rotated V image (0 conflicts). R10's x32-PV LDS round-trip
// regressed (latency chain + conflicts) -- do not reintroduce.
// R11: Q,K stored ROW-MAJOR [B,S,D] by gemm<0> (coalesced epilogue stores,
// same addressing as MODE 1); flash reads head-slices at row stride 1024.

typedef __attribute__((ext_vector_type(8))) short bf16x8;
typedef __attribute__((ext_vector_type(4))) short bf16x4;
typedef __attribute__((ext_vector_type(4))) float f32x4;
typedef unsigned short u16;
typedef unsigned int u32;

#define AS1 __attribute__((address_space(1)))
#define AS3 __attribute__((address_space(3)))

#define SCALE_L2E 0.18033688011112042f  // 0.125 * log2(e)

__device__ __forceinline__ void gld_lds16(const void* g, void* l) {
  // async global->LDS DMA: lane i's 16B land at (wave-uniform) l + i*16
  __builtin_amdgcn_global_load_lds((const AS1 void*)g, (AS3 void*)l, 16, 0, 0);
}

__device__ __forceinline__ u16 f2bf(float f) {
  u32 x = __builtin_bit_cast(u32, f);
  x += 0x7fff + ((x >> 16) & 1);  // RNE
  return (u16)(x >> 16);
}

__device__ __forceinline__ u16 f2bf_fast(float a) {
#if __has_builtin(__builtin_amdgcn_cvt_pk_bf16_f32)
  auto v = __builtin_amdgcn_cvt_pk_bf16_f32(a, a);  // both halves = a: order-immune
  return (u16)(__builtin_bit_cast(u32, v) & 0xffffu);
#else
  return f2bf(a);
#endif
}

__device__ __forceinline__ bf16x4 pack_bf16x4(float a, float b, float c, float d) {
#if __has_builtin(__builtin_amdgcn_cvt_pk_bf16_f32)
  u32 lo = __builtin_bit_cast(u32, __builtin_amdgcn_cvt_pk_bf16_f32(a, b));  // lo16=a
  u32 hi = __builtin_bit_cast(u32, __builtin_amdgcn_cvt_pk_bf16_f32(c, d));
#else
  u32 lo = (u32)f2bf(a) | ((u32)f2bf(b) << 16);
  u32 hi = (u32)f2bf(c) | ((u32)f2bf(d) << 16);
#endif
  union { u32 w[2]; bf16x4 v; } u;
  u.w[0] = lo; u.w[1] = hi;
  return u.v;
}

__device__ __forceinline__ f32x4 mfma16(bf16x4 a, bf16x4 b, f32x4 c) {
#if __has_builtin(__builtin_amdgcn_mfma_f32_16x16x16_bf16)
  return __builtin_amdgcn_mfma_f32_16x16x16_bf16(a, b, c, 0, 0, 0);
#else
  return __builtin_amdgcn_mfma_f32_16x16x16bf16_1k(a, b, c, 0, 0, 0);
#endif
}

__device__ __forceinline__ float exp2_fast(float x) {
#if __has_builtin(__builtin_amdgcn_exp2f)
  return __builtin_amdgcn_exp2f(x);
#else
  return exp2f(x);
#endif
}

// ---------------------------------------------------------------------------
// fp32 -> bf16 conversion of x (8M elements)
// ---------------------------------------------------------------------------
__global__ __launch_bounds__(256) void convert_x(const float* __restrict__ x,
                                                 u16* __restrict__ xb) {
  int i = (blockIdx.x * 256 + threadIdx.x) * 4;
  float4 v = *(const float4*)(x + i);
  ushort4 o;
  o.x = f2bf(v.x); o.y = f2bf(v.y); o.z = f2bf(v.z); o.w = f2bf(v.w);
  *(ushort4*)(xb + i) = o;
}

// ---------------------------------------------------------------------------
// Weight pack (fp32 [K][N] -> bf16 [N][K]); wq scaled by SCALE*log2(e)
// ---------------------------------------------------------------------------
__global__ __launch_bounds__(256) void pack_weights(
    const float* __restrict__ wq, const float* __restrict__ wk,
    const float* __restrict__ wv, const float* __restrict__ wo,
    u16* __restrict__ wt_qkv, u16* __restrict__ wt_o) {
  __shared__ float tile[64][65];
  int mat = blockIdx.z;
  const float* src = (mat == 0) ? wq : (mat == 1) ? wk : (mat == 2) ? wv : wo;
  int k0 = blockIdx.y * 64, j0 = blockIdx.x * 64;
  int t = threadIdx.x;
  int lr = t >> 6;   // 0..3
  int lc = t & 63;
#pragma unroll
  for (int it = 0; it < 16; ++it) {
    int r = it * 4 + lr;
    tile[r][lc] = src[(size_t)(k0 + r) * 1024 + j0 + lc];
  }
  __syncthreads();
  u16* dst = (mat == 3) ? wt_o : (wt_qkv + (size_t)mat * 1024 * 1024);
#pragma unroll
  for (int it = 0; it < 16; ++it) {
    int nl = it * 4 + lr;
    float v = tile[lc][nl];
    if (mat == 0) v *= SCALE_L2E;  // fold attention scale + log2(e)
    dst[(size_t)(j0 + nl) * 1024 + k0 + lc] = f2bf(v);
  }
}

// ---------------------------------------------------------------------------
// GEMM: C[M,N] = A[M,1024](bf16) x Bt[N,1024]^T(bf16) + bias(fp32).
// 128x128 tile, 4 waves 2x2, each wave 4x4 of 16x16x32 bf16 MFMA (m97 struct).
// 1D grid, XCD-swizzled for L2 locality.
// MODE 0: N=3072 fused QKV.
//   Q,K -> row-major [B,S,D] bf16 (coalesced stores, same addressing as MODE 1)
//   V   -> pre-rotated chunked image for flash (per bh, 64-s chunk ci:
//          [sg=0..15][slot=0..63] 8B entries, slot=(hd+4*sg)&63; flash stages
//          it as a flat linear DMA and reads b64 at the bank floor).
// MODE 1: N=1024; plain row-major fp32 out + bias
// ---------------------------------------------------------------------------
template <int MODE>
__global__ __launch_bounds__(256, 2) void gemm_bt(
    const u16* __restrict__ A, const u16* __restrict__ Bt,
    const float* __restrict__ bias0, const float* __restrict__ bias1,
    const float* __restrict__ bias2,
    void* __restrict__ out0v, void* __restrict__ out1v, void* __restrict__ out2v) {
  __shared__ u16 lA[128 * 32];  // [m][k] rows of 32 bf16 (64B)
  __shared__ u16 lB[128 * 32];  // [n][k]
  const int K = 1024;
  int tid = threadIdx.x;
  int wave = tid >> 6, lane = tid & 63;

  int bid = blockIdx.x;
  int m0, n0;
  if constexpr (MODE == 0) {
    int xcd = bid & 7, j = bid >> 3;      // 192 blocks per XCD
    n0 = (xcd * 3 + j % 3) * 128;         // XCD owns n-tiles 3x..3x+2 (768KB B)
    m0 = (j / 3) * 128;                   // consecutive j share m-tile
  } else {
    n0 = (bid & 7) * 128;                 // XCD owns 1 n-tile (256KB B)
    m0 = (bid >> 3) * 128;
  }
  int wm = (wave & 1) * 64, wn = (wave >> 1) * 64;

  f32x4 acc[4][4];
#pragma unroll
  for (int i = 0; i < 4; ++i)
#pragma unroll
    for (int j = 0; j < 4; ++j) acc[i][j] = f32x4{0.f, 0.f, 0.f, 0.f};

  int srow = lane >> 2;          // source row within 16-row stage
  int scol = (lane & 3) * 8;     // source col chunk within 32

  for (int k0 = 0; k0 < K; k0 += 32) {
#pragma unroll
    for (int c = 0; c < 2; ++c) {
      int rbase = wave * 32 + c * 16;
      gld_lds16(A + (size_t)(m0 + rbase + srow) * K + k0 + scol, lA + rbase * 32);
      gld_lds16(Bt + (size_t)(n0 + rbase + srow) * K + k0 + scol, lB + rbase * 32);
    }
    __syncthreads();
    bf16x8 af[4], bfr[4];
#pragma unroll
    for (int mt = 0; mt < 4; ++mt)
      af[mt] = *(const bf16x8*)(lA + (wm + mt * 16 + (lane & 15)) * 32 + (lane >> 4) * 8);
#pragma unroll
    for (int nt = 0; nt < 4; ++nt)
      bfr[nt] = *(const bf16x8*)(lB + (wn + nt * 16 + (lane & 15)) * 32 + (lane >> 4) * 8);
#pragma unroll
    for (int mt = 0; mt < 4; ++mt)
#pragma unroll
      for (int nt = 0; nt < 4; ++nt)
        acc[mt][nt] = __builtin_amdgcn_mfma_f32_16x16x32_bf16(af[mt], bfr[nt], acc[mt][nt], 0, 0, 0);
    __syncthreads();
  }

  // epilogue: C/D layout row=(lane>>4)*4+r, col=lane&15 (m89-verified)
  int rbase0 = m0 + wm + (lane >> 4) * 4;
  int cbase = n0 + wn + (lane & 15);
#pragma unroll
  for (int nt = 0; nt < 4; ++nt) {
    int col = cbase + nt * 16;
    if constexpr (MODE == 0) {
      int mat = col >> 10, j = col & 1023;
      const float* bp = (mat == 0) ? bias0 : (mat == 1) ? bias1 : bias2;
      float bv = bp[j];
      if (mat == 0) bv *= SCALE_L2E;
      if (mat == 2) {
        // V rotated-chunk image: 4 consecutive s per lane -> one 8B entry
        int h = j >> 6, hd = j & 63;
        u16* base = (u16*)out2v;
#pragma unroll
        for (int mt = 0; mt < 4; ++mt) {
          int row0 = rbase0 + mt * 16;  // multiple of 4, no b/s crossing
          int b = row0 >> 11, s = row0 & 2047;
          int ci = s >> 6, sg = (s >> 2) & 15;
          int slot = (hd + 4 * sg) & 63;
          size_t off = (size_t)(b * 16 + h) * 131072 + ci * 4096 + sg * 256 + slot * 4;
          ushort4 pk;
          pk.x = f2bf_fast(acc[mt][nt][0] + bv);
          pk.y = f2bf_fast(acc[mt][nt][1] + bv);
          pk.z = f2bf_fast(acc[mt][nt][2] + bv);
          pk.w = f2bf_fast(acc[mt][nt][3] + bv);
          *(ushort4*)(base + off) = pk;
        }
      } else {
        // Q,K row-major [B,S,D]: coalesced (consecutive lanes -> consecutive j)
        u16* base = (mat == 0) ? (u16*)out0v : (u16*)out1v;
#pragma unroll
        for (int mt = 0; mt < 4; ++mt)
#pragma unroll
          for (int r = 0; r < 4; ++r) {
            int row = rbase0 + mt * 16 + r;
            base[(size_t)row * 1024 + j] = f2bf_fast(acc[mt][nt][r] + bv);
          }
      }
    } else {
      float bv = bias0[col];
      float* o = (float*)out0v;
#pragma unroll
      for (int mt = 0; mt < 4; ++mt)
#pragma unroll
        for (int r = 0; r < 4; ++r) {
          int row = rbase0 + mt * 16 + r;
          o[(size_t)row * 1024 + col] = acc[mt][nt][r] + bv;
        }
    }
  }
}

// ---------------------------------------------------------------------------
// Flash attention (R9 structure, 99.7us): register-resident P, 64 q/wave,
// fixed-max softmax. 1 block per (b, h, 256 q-rows); 4 waves x 4 q-tiles.
// Per KV-64 iter, per s-tile st:
//   S^T[s][q] = mfma_16x16x32(A=K-frag, B=Q-frag)   (t=0..3 q-tiles)
//   P^T = exp2(S^T) packed bf16x4 (B-operand layout, registers)
//   O^T[d][q] += mfma_16x16x16(A=V-frag (b64 from rotated lV), B=P^T)
// Q,K are row-major [B,S,D]: head slice at col h*64, row stride 1024.
// K: XOR-swizzled staging (b128 reads conflict-free). V: linear DMA of the
// pre-rotated image; b64 reads at uniform bank floor (measured 0 conflicts).
// ---------------------------------------------------------------------------
__global__ __launch_bounds__(256, 2) void flash_attn(
    const u16* __restrict__ Q, const u16* __restrict__ Kb,
    const u16* __restrict__ Vg, u16* __restrict__ ctx) {
  __shared__ u16 lK[2][64 * 32];  // [k-half][kv-row][32] xor-swizzled (8KB)
  __shared__ u16 lV[4096];        // rotated chunk image [sg][slot] 8B entries (8KB)
  int tid = threadIdx.x, wave = tid >> 6, lane = tid & 63;

  int F = blockIdx.x;             // 512 flat blocks
  int xcd = F & 7, idx = F >> 3;  // 64 per XCD
  int bh = xcd * 8 + (idx >> 3);  // 8 bh per XCD; q-blocks of a bh adjacent
  int q0 = (idx & 7) * 256;
  int b = bh >> 4, h = bh & 15;
  const u16* Qp = Q + (size_t)b * 2048 * 1024 + h * 64;   // row-major head slice
  const u16* Kp = Kb + (size_t)b * 2048 * 1024 + h * 64;
  const u16* Vp = Vg + (size_t)bh * 131072;

  int c = lane & 15, g = lane >> 4;

  // Q B-fragments (persistent): lane holds q=c of tile t, k=kk*32+g*8+j
  bf16x8 qf[4][2];
#pragma unroll
  for (int t = 0; t < 4; ++t) {
    const u16* qrow = Qp + (size_t)(q0 + wave * 64 + t * 16 + c) * 1024 + g * 8;
    qf[t][0] = *(const bf16x8*)qrow;
    qf[t][1] = *(const bf16x8*)(qrow + 32);
  }

  float lsum[4] = {0.f, 0.f, 0.f, 0.f};  // per-lane: q=c of tile t
  f32x4 o[4][4];                          // O^T[d=dt*16+4g+r][q=c] per tile t
#pragma unroll
  for (int t = 0; t < 4; ++t)
#pragma unroll
    for (int dt = 0; dt < 4; ++dt) o[t][dt] = f32x4{0.f, 0.f, 0.f, 0.f};

  // K staging: lane stages row wave*16+(lane>>2), chunk-pos lane&3;
  // source chunk = pos ^ ((row>>1)&3)   (XOR swizzle; b128 reads conflict-free)
  int srow = lane >> 2;
  int schunk = (((lane & 3) ^ ((lane >> 3) & 3)) * 8);
  int rsw = (c >> 1) & 3;  // K read-side swizzle
  int stg_row = wave * 16 + srow;
  int vrot = c + 4 * g;    // V slot base (rotation partial; +16*st+16*dt at use)

  for (int s0 = 0; s0 < 2048; s0 += 64) {
#pragma unroll
    for (int kk = 0; kk < 2; ++kk)
      gld_lds16(Kp + (size_t)(s0 + stg_row) * 1024 + kk * 32 + schunk,
                lK[kk] + wave * 512);
    // V: flat linear copy of the pre-rotated chunk (8KB; 2KB per wave)
#pragma unroll
    for (int vv = 0; vv < 2; ++vv)
      gld_lds16(Vp + (size_t)s0 * 64 + wave * 1024 + vv * 512 + lane * 8,
                lV + wave * 1024 + vv * 512);
    __syncthreads();

#pragma unroll
    for (int st = 0; st < 4; ++st) {
      // K A-fragments: lane holds kv=st*16+c, k=kk*32+g*8+j
      bf16x8 kf0 = *(const bf16x8*)(lK[0] + (st * 16 + c) * 32 + (g ^ rsw) * 8);
      bf16x8 kf1 = *(const bf16x8*)(lK[1] + (st * 16 + c) * 32 + (g ^ rsw) * 8);

      bf16x4 pf[4];
#pragma unroll
      for (int t = 0; t < 4; ++t) {
        f32x4 sa = __builtin_amdgcn_mfma_f32_16x16x32_bf16(kf0, qf[t][0],
                       f32x4{0.f, 0.f, 0.f, 0.f}, 0, 0, 0);
        sa = __builtin_amdgcn_mfma_f32_16x16x32_bf16(kf1, qf[t][1], sa, 0, 0, 0);
        // sa[r] = S^T[s=st*16+4g+r][q=c] (log2 units)
        float p0 = exp2_fast(sa[0]), p1 = exp2_fast(sa[1]);
        float p2 = exp2_fast(sa[2]), p3 = exp2_fast(sa[3]);
        lsum[t] += (p0 + p1) + (p2 + p3);
        pf[t] = pack_bf16x4(p0, p1, p2, p3);  // B-frag: k=4g+j, n=q=c
      }

      // O^T += V^T[:, st-slice] P^T[st-slice, :]
      int sg = st * 4 + g;
      int rotb = (vrot + 16 * st) & 63;     // slot = (d + 4*sg) & 63, d=dt*16+c
#pragma unroll
      for (int dt = 0; dt < 4; ++dt) {
        bf16x4 vf = *(const bf16x4*)(lV + sg * 256 + (((rotb + dt * 16) & 63) << 2));
#pragma unroll
        for (int t = 0; t < 4; ++t)
          o[t][dt] = mfma16(vf, pf[t], o[t][dt]);
      }
    }
    __syncthreads();
  }

  // epilogue: reduce lsum across the 4 lane-groups sharing q=c, normalize,
  // write ctx[b][q][h][d] as packed ushort4 (d = dt*16+4g+r)
#pragma unroll
  for (int t = 0; t < 4; ++t) {
    float rs = lsum[t];
    rs += __shfl_xor(rs, 16);
    rs += __shfl_xor(rs, 32);
    float inv = 1.0f / fmaxf(rs, 1e-30f);
    int q = q0 + wave * 64 + t * 16 + c;
    size_t rowbase = ((size_t)(b * 2048 + q) * 16 + h) * 64;
#pragma unroll
    for (int dt = 0; dt < 4; ++dt) {
      ushort4 pk;
      pk.x = f2bf_fast(o[t][dt][0] * inv);
      pk.y = f2bf_fast(o[t][dt][1] * inv);
      pk.z = f2bf_fast(o[t][dt][2] * inv);
      pk.w = f2bf_fast(o[t][dt][3] * inv);
      *(ushort4*)(ctx + rowbase + dt * 16 + g * 4) = pk;
    }
  }
}

// ---------------------------------------------------------------------------
extern "C" void kernel_launch(void* const* d_in, const int* in_sizes, int n_in,
                              void* d_out, int out_size, void* d_ws, size_t ws_size,
                              hipStream_t stream) {
  const float* x  = (const float*)d_in[0];
  const float* wq = (const float*)d_in[1];
  const float* bq = (const float*)d_in[2];
  const float* wk = (const float*)d_in[3];
  const float* bk = (const float*)d_in[4];
  const float* wv = (const float*)d_in[5];
  const float* bv = (const float*)d_in[6];
  const float* wo = (const float*)d_in[7];
  const float* bo = (const float*)d_in[8];

  u16* ws = (u16*)d_ws;
  u16* xb     = ws;                            // 8192*1024 bf16 (16MB)
  u16* wt_qkv = xb + (size_t)8192 * 1024;      // 3072*1024 (6MB)
  u16* wt_o   = wt_qkv + (size_t)3072 * 1024;  // 1024*1024 (2MB)
  u16* Qb     = wt_o + (size_t)1024 * 1024;    // row-major [B,S,D] (16MB)
  u16* Kbuf   = Qb + (size_t)8192 * 1024;      // row-major [B,S,D] (16MB)
  u16* Vgb    = Kbuf + (size_t)8192 * 1024;    // rotated chunk image (16MB)
  u16* ctx    = Vgb + (size_t)8192 * 1024;     // [B,S,D] bf16 (16MB)
  // total ws use: 88MB

  convert_x<<<8192, 256, 0, stream>>>(x, xb);
  pack_weights<<<dim3(16, 16, 4), 256, 0, stream>>>(wq, wk, wv, wo, wt_qkv, wt_o);
  gemm_bt<0><<<1536, 256, 0, stream>>>(xb, wt_qkv, bq, bk, bv, Qb, Kbuf, Vgb);
  flash_attn<<<512, 256, 0, stream>>>(Qb, Kbuf, Vgb, ctx);
  gemm_bt<1><<<512, 256, 0, stream>>>(ctx, wt_o, bo, nullptr, nullptr,
                                      d_out, nullptr, nullptr);
}